// Round 1
// 466.718 us; speedup vs baseline: 1.1376x; 1.1376x over previous
//
#include <hip/hip_runtime.h>
#include <hip/hip_bf16.h>

// R11: R10 structure, minus the alpha-phase atomic, plus Wh folded into gather tables.
//   Sb = bf16(hidden @ Ws.T), Rb = bf16(rela @ Wr.T), Qb = bf16(q proj)   [packed 2/uint]
//   hist+pack: rank = counts[obj]++ (atomic RETURN reused);
//              pk2[e] = {sub|rel<<17, obj|ridx<<17|rank<<20}
//   multi-block exclusive scan -> offs (no cur array, no second atomic pass)
//   alpha+scatter: 4 edges per 16-lane group (latency chain amortized 4x);
//                  pos = offs[obj] + rank; rec[pos] = {alpha, sub|rel<<17}
//   Hw = bf16(hidden @ Wh.T), Rw = bf16(rela @ Wh.T)  [after scatter, overlaying pk2]
//   reduce: one wave per node, 4 records in flight, bf16x4 gathers -> FINAL d_out
//   (outgemm eliminated: Wh applied before aggregation; error is identical since
//    bf16 rounding noise passes through Wh linearly in either ordering)

__device__ inline unsigned short f2bf(float x) {
    unsigned u = __float_as_uint(x);
    u += 0x7FFF + ((u >> 16) & 1);          // round-to-nearest-even
    return (unsigned short)(u >> 16);
}
__device__ inline float bf2f(unsigned short b) {
    return __uint_as_float(((unsigned)b) << 16);
}

// out[n][k] = sum_d X[n][d]*W[k][d], k<32, d<64; emitted as bf16 pairs (uint)
__global__ void proj32_bf16_kernel(const float* __restrict__ X, const float* __restrict__ W,
                                   unsigned* __restrict__ out, int nrows) {
    __shared__ float wT[64 * 32];
    int tid = threadIdx.x;
    for (int i = tid; i < 32 * 64; i += 256) {
        int k = i >> 6, d = i & 63;
        wT[d * 32 + k] = W[i];
    }
    __syncthreads();
    int row = blockIdx.x * 8 + (tid >> 5);
    int k = tid & 31;
    if (row >= nrows) return;
    const float4* X4 = (const float4*)(X + (size_t)row * 64);
    float acc = 0.f;
#pragma unroll
    for (int d4 = 0; d4 < 16; ++d4) {
        float4 x = X4[d4];
        int d = d4 * 4;
        acc += x.x * wT[(d + 0) * 32 + k] + x.y * wT[(d + 1) * 32 + k]
             + x.z * wT[(d + 2) * 32 + k] + x.w * wT[(d + 3) * 32 + k];
    }
    float other = __shfl_xor(acc, 1, 64);   // pair partner (k^1)
    if ((k & 1) == 0) {
        unsigned lo = f2bf(acc), hi = f2bf(other);
        out[(size_t)row * 16 + (k >> 1)] = lo | (hi << 16);
    }
}

__global__ void qproj_bf16_kernel(const int* __restrict__ q_rel, const float* __restrict__ rela,
                                  const float* __restrict__ Wqr, const float* __restrict__ bqr,
                                  unsigned* __restrict__ Qb, int batch) {
    int tid = threadIdx.x;
    int b = tid >> 5, k = tid & 31;
    if (b >= batch) return;
    int qr = q_rel[b];
    const float* x = rela + (size_t)qr * 64;
    const float* w = Wqr + (size_t)k * 64;
    float acc = bqr[k];
    for (int d = 0; d < 64; ++d) acc += w[d] * x[d];
    float other = __shfl_xor(acc, 1, 64);
    if ((k & 1) == 0) {
        unsigned lo = f2bf(acc), hi = f2bf(other);
        Qb[b * 16 + (k >> 1)] = lo | (hi << 16);
    }
}

// out[n][k] = sum_d X[n][d]*W[k][d], k<64, d<64; bf16 output (2B/lane, coalesced)
__global__ void proj64_bf16_kernel(const float* __restrict__ X, const float* __restrict__ W,
                                   unsigned short* __restrict__ out, int nrows) {
    __shared__ float wT[64 * 64];   // wT[d*64+j] = W[j*64+d]
    int tid = threadIdx.x;
    for (int i = tid; i < 64 * 64; i += 256) {
        int j = i >> 6, d = i & 63;
        wT[d * 64 + j] = W[i];
    }
    __syncthreads();
    int wave = tid >> 6, j = tid & 63;
    int base = blockIdx.x * 32;
    for (int r = wave; r < 32; r += 4) {
        int row = base + r;
        if (row >= nrows) break;
        const float4* rp = (const float4*)(X + (size_t)row * 64);
        float acc = 0.f;
#pragma unroll
        for (int d4 = 0; d4 < 16; ++d4) {
            float4 m4 = rp[d4];              // wave-uniform broadcast load
            int d = d4 * 4;
            acc += m4.x * wT[(d + 0) * 64 + j] + m4.y * wT[(d + 1) * 64 + j]
                 + m4.z * wT[(d + 2) * 64 + j] + m4.w * wT[(d + 3) * 64 + j];
        }
        out[(size_t)row * 64 + j] = f2bf(acc);
    }
}

// one thread per edge: histogram of obj, keep the atomic's RETURN as the
// within-node rank, pack everything into dense 8B records.
// pk2[e].y layout: obj[0:17) | ridx[17:20) | rank[20:32)
__global__ void hist_pack_kernel(const int* __restrict__ edges, int* __restrict__ counts,
                                 int2* __restrict__ pk2, int n_edge) {
    int e = blockIdx.x * 256 + threadIdx.x;
    if (e >= n_edge) return;
    const int* ep = edges + (size_t)e * 6;
    int2 a01 = *(const int2*)ep;        // {r_idx, pad}
    int2 a23 = *(const int2*)(ep + 2);  // {rel, pad}
    int2 a45 = *(const int2*)(ep + 4);  // {sub, obj}
    int rank = atomicAdd(&counts[a45.y], 1);
    pk2[e] = make_int2(a45.x | (a23.x << 17),
                       a45.y | (a01.x << 17) | (rank << 20));
}

// ---- multi-block exclusive scan (counts[0..N) -> offs[0..N]) ----
#define SCAN_CHUNK 1024

__global__ void scan_partial_kernel(const int* __restrict__ counts, int* __restrict__ bsum,
                                    int N) {
    __shared__ int s[256];
    int base = blockIdx.x * SCAN_CHUNK;
    int tid = threadIdx.x;
    int sum = 0;
#pragma unroll
    for (int k = 0; k < 4; ++k) {
        int idx = base + k * 256 + tid;
        if (idx < N) sum += counts[idx];
    }
    s[tid] = sum;
    __syncthreads();
    for (int off = 128; off > 0; off >>= 1) {
        if (tid < off) s[tid] += s[tid + off];
        __syncthreads();
    }
    if (tid == 0) bsum[blockIdx.x] = s[0];
}

__global__ void scan_bsum_kernel(int* __restrict__ bsum, int* __restrict__ offs, int B, int N) {
    __shared__ int s[1024];
    int tid = threadIdx.x;
    int v = (tid < B) ? bsum[tid] : 0;
    s[tid] = v;
    __syncthreads();
    for (int off = 1; off < 1024; off <<= 1) {
        int t = (tid >= off) ? s[tid - off] : 0;
        __syncthreads();
        s[tid] += t;
        __syncthreads();
    }
    if (tid < B) bsum[tid] = s[tid] - v;   // exclusive block prefix
    if (tid == 0) offs[N] = s[1023];       // grand total
}

__global__ void scan_final_kernel(const int* __restrict__ counts, const int* __restrict__ bsum,
                                  int* __restrict__ offs, int N) {
    __shared__ int s[256];
    int base = blockIdx.x * SCAN_CHUNK;
    int tid = threadIdx.x;
    int v[4];
    int sum = 0;
#pragma unroll
    for (int k = 0; k < 4; ++k) {
        int idx = base + tid * 4 + k;
        v[k] = (idx < N) ? counts[idx] : 0;
        sum += v[k];
    }
    s[tid] = sum;
    __syncthreads();
    for (int off = 1; off < 256; off <<= 1) {
        int t = (tid >= off) ? s[tid - off] : 0;
        __syncthreads();
        s[tid] += t;
        __syncthreads();
    }
    int run = bsum[blockIdx.x] + s[tid] - sum;
#pragma unroll
    for (int k = 0; k < 4; ++k) {
        int idx = base + tid * 4 + k;
        if (idx < N) offs[idx] = run;
        run += v[k];
    }
}

__device__ inline float edot(unsigned sv, unsigned rv, unsigned qv, float2 w) {
    float a0 = fmaxf(bf2f((unsigned short)sv) + bf2f((unsigned short)rv)
                     + bf2f((unsigned short)qv), 0.f);
    float a1 = fmaxf(bf2f((unsigned short)(sv >> 16)) + bf2f((unsigned short)(rv >> 16))
                     + bf2f((unsigned short)(qv >> 16)), 0.f);
    return a0 * w.x + a1 * w.y;
}

// 16 lanes per group, FOUR edges per group: all headers + all 12 gathers issue
// independently (latency chain amortized 4x), then 4 interleaved shuffle reduces;
// lanes 0..3 each finalize one edge. No atomic: pos = offs[obj] + packed rank.
__global__ void alpha_scatter_kernel(const int2* __restrict__ pk2,
                                     const unsigned* __restrict__ Sb,
                                     const unsigned* __restrict__ Rb,
                                     const unsigned* __restrict__ Qb,
                                     const float2* __restrict__ w2,
                                     const float* __restrict__ w_alpha_b,
                                     const int* __restrict__ offs,
                                     float2* __restrict__ rec,
                                     int n_edge) {
    int tid = threadIdx.x;
    int lane = tid & 15;
    int e0 = (blockIdx.x * 16 + (tid >> 4)) * 4;
    if (e0 >= n_edge) return;
    int eN = n_edge - 1;
    int2 h0 = pk2[e0];
    int2 h1 = pk2[min(e0 + 1, eN)];
    int2 h2 = pk2[min(e0 + 2, eN)];
    int2 h3 = pk2[min(e0 + 3, eN)];
    float2 w = w2[lane];
    unsigned sv0 = Sb[(size_t)(h0.x & 0x1FFFF) * 16 + lane];
    unsigned sv1 = Sb[(size_t)(h1.x & 0x1FFFF) * 16 + lane];
    unsigned sv2 = Sb[(size_t)(h2.x & 0x1FFFF) * 16 + lane];
    unsigned sv3 = Sb[(size_t)(h3.x & 0x1FFFF) * 16 + lane];
    unsigned rv0 = Rb[(size_t)(h0.x >> 17) * 16 + lane];
    unsigned rv1 = Rb[(size_t)(h1.x >> 17) * 16 + lane];
    unsigned rv2 = Rb[(size_t)(h2.x >> 17) * 16 + lane];
    unsigned rv3 = Rb[(size_t)(h3.x >> 17) * 16 + lane];
    unsigned qv0 = Qb[((h0.y >> 17) & 7) * 16 + lane];
    unsigned qv1 = Qb[((h1.y >> 17) & 7) * 16 + lane];
    unsigned qv2 = Qb[((h2.y >> 17) & 7) * 16 + lane];
    unsigned qv3 = Qb[((h3.y >> 17) & 7) * 16 + lane];
    float p0 = edot(sv0, rv0, qv0, w);
    float p1 = edot(sv1, rv1, qv1, w);
    float p2 = edot(sv2, rv2, qv2, w);
    float p3 = edot(sv3, rv3, qv3, w);
#pragma unroll
    for (int off = 8; off > 0; off >>= 1) {
        p0 += __shfl_xor(p0, off, 16);
        p1 += __shfl_xor(p1, off, 16);
        p2 += __shfl_xor(p2, off, 16);
        p3 += __shfl_xor(p3, off, 16);
    }
    if (lane < 4 && e0 + lane < n_edge) {
        float p = p0; int2 h = h0;
        if (lane == 1) { p = p1; h = h1; }
        if (lane == 2) { p = p2; h = h2; }
        if (lane == 3) { p = p3; h = h3; }
        float alpha = 1.f / (1.f + __expf(-(p + w_alpha_b[0])));
        int obj  = h.y & 0x1FFFF;
        int rank = (int)(((unsigned)h.y) >> 20);
        int pos = offs[obj] + rank;
        float2 out;
        out.x = alpha;
        out.y = __int_as_float(h.x);            // sub | rel<<17
        rec[pos] = out;
    }
}

// one 64-lane wave per node; 4 records in flight; bf16x4 gathers of the
// Wh-PROJECTED tables -> final output rows (f32)
__global__ void reduce_kernel(const float2* __restrict__ rec, const int* __restrict__ offs,
                              const ushort4* __restrict__ Hw4,
                              const ushort4* __restrict__ Rw4,
                              float4* __restrict__ out4, int n_node) {
    int lane = threadIdx.x & 63;
    int node = blockIdx.x * 4 + (threadIdx.x >> 6);
    if (node >= n_node) return;
    int g = lane >> 4;        // record subgroup 0..3
    int t = lane & 15;        // dim-quad index 0..15
    int start = offs[node], end = offs[node + 1];
    float4 acc = make_float4(0.f, 0.f, 0.f, 0.f);
    for (int i = start; i < end; i += 64) {
        int m = end - i;
        if (m > 64) m = 64;
        float a = 0.f;        // a=0 for idle lanes -> tail records contribute 0
        int pk = 0;
        if (lane < m) {
            float2 r = rec[i + lane];
            a = r.x;
            pk = __float_as_int(r.y);
        }
        for (int j = 0; 4 * j < m; ++j) {
            int src = 4 * j + g;
            float aj = __shfl(a, src, 64);
            int pkj = __shfl(pk, src, 64);
            int sub = pkj & 0x1FFFF, rel = pkj >> 17;
            ushort4 hu = Hw4[(size_t)sub * 16 + t];
            ushort4 ru = Rw4[(size_t)rel * 16 + t];
            acc.x += aj * (bf2f(hu.x) + bf2f(ru.x));
            acc.y += aj * (bf2f(hu.y) + bf2f(ru.y));
            acc.z += aj * (bf2f(hu.z) + bf2f(ru.z));
            acc.w += aj * (bf2f(hu.w) + bf2f(ru.w));
        }
    }
#pragma unroll
    for (int off = 16; off <= 32; off <<= 1) {
        acc.x += __shfl_xor(acc.x, off, 64);
        acc.y += __shfl_xor(acc.y, off, 64);
        acc.z += __shfl_xor(acc.z, off, 64);
        acc.w += __shfl_xor(acc.w, off, 64);
    }
    if (g == 0) out4[(size_t)node * 16 + t] = acc;
}

extern "C" void kernel_launch(void* const* d_in, const int* in_sizes, int n_in,
                              void* d_out, int out_size, void* d_ws, size_t ws_size,
                              hipStream_t stream) {
    const int*   q_rel     = (const int*)d_in[1];
    const float* hidden    = (const float*)d_in[2];
    const int*   edges     = (const int*)d_in[3];
    const float* rela      = (const float*)d_in[7];
    const float* Ws        = (const float*)d_in[8];
    const float* Wr        = (const float*)d_in[9];
    const float* Wqr       = (const float*)d_in[10];
    const float* bqr       = (const float*)d_in[11];
    const float* w_alpha_w = (const float*)d_in[12];
    const float* w_alpha_b = (const float*)d_in[13];
    const float* Wh        = (const float*)d_in[14];

    int n_node = in_sizes[2] / 64;
    int n_edge = in_sizes[3] / 6;
    int n_rel  = in_sizes[7] / 64;
    int batch  = in_sizes[1];

    int n_sblk = (n_node + SCAN_CHUNK - 1) / SCAN_CHUNK;   // scan blocks (<=1024)

    // workspace layout (~40 MB): Hw/Rw overlay pk2 (pk2 dead after alpha_scatter)
    unsigned* Sb   = (unsigned*)d_ws;                     // n_node*16 uints (6.4 MB)
    unsigned* Rb   = Sb + (size_t)n_node * 16;            // n_rel*16
    unsigned* Qb   = Rb + (size_t)n_rel * 16;             // batch*16
    int*   counts  = (int*)(Qb + (size_t)batch * 16);     // n_node
    int*   offs    = counts + n_node;                     // n_node+1
    int*   bsum    = offs + n_node + 1;                   // n_sblk
    size_t rec_off = (size_t)(bsum + n_sblk - (int*)d_ws);
    rec_off = (rec_off + 3) & ~(size_t)3;                 // align 16B
    float2* rec    = (float2*)((int*)d_ws + rec_off);     // n_edge float2 (16 MB)
    int2*  pk2     = (int2*)(rec + n_edge);               // n_edge int2 (16 MB)
    unsigned short* Hw = (unsigned short*)pk2;            // n_node*64 ushorts (12.8 MB)
    unsigned short* Rw = Hw + (size_t)n_node * 64;        // n_rel*64 (51 KB) - fits in pk2

    (void)hipMemsetAsync(counts, 0, (size_t)n_node * sizeof(int), stream);

    proj32_bf16_kernel<<<(n_node + 7) / 8, 256, 0, stream>>>(hidden, Ws, Sb, n_node);
    proj32_bf16_kernel<<<(n_rel + 7) / 8, 256, 0, stream>>>(rela, Wr, Rb, n_rel);
    qproj_bf16_kernel<<<1, 256, 0, stream>>>(q_rel, rela, Wqr, bqr, Qb, batch);

    hist_pack_kernel<<<(n_edge + 255) / 256, 256, 0, stream>>>(edges, counts, pk2, n_edge);

    scan_partial_kernel<<<n_sblk, 256, 0, stream>>>(counts, bsum, n_node);
    scan_bsum_kernel<<<1, 1024, 0, stream>>>(bsum, offs, n_sblk, n_node);
    scan_final_kernel<<<n_sblk, 256, 0, stream>>>(counts, bsum, offs, n_node);

    alpha_scatter_kernel<<<(n_edge + 63) / 64, 256, 0, stream>>>(
        pk2, Sb, Rb, Qb, (const float2*)w_alpha_w, w_alpha_b, offs, rec, n_edge);

    // build Wh-projected bf16 gather tables AFTER alpha_scatter (Hw overlays pk2)
    proj64_bf16_kernel<<<(n_node + 31) / 32, 256, 0, stream>>>(hidden, Wh, Hw, n_node);
    proj64_bf16_kernel<<<(n_rel + 31) / 32, 256, 0, stream>>>(rela, Wh, Rw, n_rel);

    reduce_kernel<<<(n_node + 3) / 4, 256, 0, stream>>>(
        rec, offs, (const ushort4*)Hw, (const ushort4*)Rw, (float4*)d_out, n_node);
}